// Round 8
// baseline (118.564 us; speedup 1.0000x reference)
//
#include <hip/hip_runtime.h>
#include <hip/hip_bf16.h>
#include <stdint.h>

#define D_MODEL 1024
#define NUM_HEADS 16
#define HEAD_DIM 64
#define BATCH 2048

typedef unsigned short u16;
typedef __bf16 bf16x8 __attribute__((ext_vector_type(8)));
typedef float f32x4 __attribute__((ext_vector_type(4)));
typedef u16 u16x8 __attribute__((ext_vector_type(8)));

typedef __attribute__((address_space(1))) void gv_t;
typedef __attribute__((address_space(3))) void lv_t;

__device__ __forceinline__ u16 f2bf(float f) {
    uint32_t u = __builtin_bit_cast(uint32_t, f);
    return (u16)((u + 0x7fffu + ((u >> 16) & 1u)) >> 16);
}
__device__ __forceinline__ f32x4 fzero4() { f32x4 v = {0.f, 0.f, 0.f, 0.f}; return v; }

template<int N> __device__ __forceinline__ void waitv() {
    if constexpr (N == 0) asm volatile("s_waitcnt vmcnt(0)" ::: "memory");
    else if constexpr (N == 2) asm volatile("s_waitcnt vmcnt(2)" ::: "memory");
    else if constexpr (N == 3) asm volatile("s_waitcnt vmcnt(3)" ::: "memory");
    else if constexpr (N == 4) asm volatile("s_waitcnt vmcnt(4)" ::: "memory");
    else if constexpr (N == 6) asm volatile("s_waitcnt vmcnt(6)" ::: "memory");
}
#define BAR() do { __builtin_amdgcn_s_barrier(); __builtin_amdgcn_sched_barrier(0); } while (0)

// ---------------------------------------------------------------- convert fp32 -> bf16
struct Conv7 {
    const float* src[7];
    u16* dst[7];
    int n[7];
};

__global__ __launch_bounds__(256) void convert_kernel(Conv7 a) {
    const int y = blockIdx.y;
    const int n = a.n[y];
    const long base = (long)(blockIdx.x * 256 + threadIdx.x) * 8;
    if (base >= n) return;
    const float* s = a.src[y] + base;
    const float4 f0 = *(const float4*)s;
    const float4 f1 = *(const float4*)(s + 4);
    u16x8 o;
    o[0] = f2bf(f0.x); o[1] = f2bf(f0.y); o[2] = f2bf(f0.z); o[3] = f2bf(f0.w);
    o[4] = f2bf(f1.x); o[5] = f2bf(f1.y); o[6] = f2bf(f1.z); o[7] = f2bf(f1.w);
    *(u16x8*)(a.dst[y] + base) = o;
}

struct G3 {
    const u16* A[3];
    const u16* Bt[3];
    const float* bias[3];
    void* C[3];
    int trans[3];
    int ldc[3];
};

// ---------------------------------------------------------------- proj GEMM, 128x128 tile, BK=32, 48KB LDS, 3 blocks/CU
// 4 waves 2x2, wave-tile 64x64 (4m x 4n fragments): 8 ds_read_b128 per 16 MFMA.
// 3-buffer depth-2 counted vmcnt (LPT=4). Swizzle: 16B slot ^= row&3 (pre-swizzled source).
__global__ __launch_bounds__(256, 3) void proj128_kernel(G3 g, int K) {
    __shared__ __align__(16) u16 As[3][128 * 32];
    __shared__ __align__(16) u16 Bs[3][128 * 32];
    const int z = blockIdx.z;
    const u16* __restrict__ A = g.A[z];
    const u16* __restrict__ Bt = g.Bt[z];
    const int tid = threadIdx.x, lane = tid & 63, wid = tid >> 6;
    const int l15 = lane & 15, l4 = lane >> 4;
    const int wr = wid >> 1, wc = wid & 1;
    const size_t brow = blockIdx.x, bcol = blockIdx.y;
    const int trow = tid >> 2;                       // 0..63
    const int cswz = ((tid & 3) ^ (trow & 3)) * 8;   // pre-swizzled source column
    const int sa = l15 & 3;                          // row&3 for fragment reads

    const u16* Ag = A + (brow * 128 + trow) * (size_t)K + cswz;
    const u16* Bg = Bt + (bcol * 128 + trow) * (size_t)K + cswz;

    f32x4 acc[4][4];
#pragma unroll
    for (int m = 0; m < 4; m++)
#pragma unroll
        for (int n = 0; n < 4; n++) acc[m][n] = fzero4();

#define STGP(bi, k0) do { \
        __builtin_amdgcn_global_load_lds((gv_t*)(Ag + (k0)), (lv_t*)(&As[bi][tid * 8]), 16, 0, 0); \
        __builtin_amdgcn_global_load_lds((gv_t*)(Ag + (size_t)64 * K + (k0)), (lv_t*)(&As[bi][tid * 8 + 2048]), 16, 0, 0); \
        __builtin_amdgcn_global_load_lds((gv_t*)(Bg + (k0)), (lv_t*)(&Bs[bi][tid * 8]), 16, 0, 0); \
        __builtin_amdgcn_global_load_lds((gv_t*)(Bg + (size_t)64 * K + (k0)), (lv_t*)(&Bs[bi][tid * 8 + 2048]), 16, 0, 0); \
    } while (0)

    const int NT = K / 32;
    STGP(0, 0);
    STGP(1, 32);
    int cur = 0, pf = 2;
    for (int t = 0; t < NT; ++t) {
        if (t + 1 < NT) waitv<4>(); else waitv<0>();
        BAR();
        bf16x8 a[4], b[4];
#pragma unroll
        for (int m = 0; m < 4; m++) {
            const int row = wr * 64 + m * 16 + l15;
            a[m] = *(const bf16x8*)&As[cur][row * 32 + ((l4 ^ sa) * 8)];
        }
#pragma unroll
        for (int n = 0; n < 4; n++) {
            const int row = wc * 64 + n * 16 + l15;
            b[n] = *(const bf16x8*)&Bs[cur][row * 32 + ((l4 ^ sa) * 8)];
        }
        if (t + 2 < NT) STGP(pf, (t + 2) * 32);
        __builtin_amdgcn_s_setprio(1);
#pragma unroll
        for (int m = 0; m < 4; m++)
#pragma unroll
            for (int n = 0; n < 4; n++)
                acc[m][n] = __builtin_amdgcn_mfma_f32_16x16x32_bf16(a[m], b[n], acc[m][n], 0, 0, 0);
        __builtin_amdgcn_s_setprio(0);
        cur = (cur == 2) ? 0 : cur + 1;
        pf = (pf == 2) ? 0 : pf + 1;
    }
#undef STGP

    const int trans = g.trans[z];
    const size_t ldc = g.ldc[z];
    const float* bias = g.bias[z];
#pragma unroll
    for (int m = 0; m < 4; m++)
#pragma unroll
        for (int n = 0; n < 4; n++) {
            const size_t col = bcol * 128 + wc * 64 + n * 16 + l15;
            const float bv = bias[col];
#pragma unroll
            for (int j = 0; j < 4; j++) {
                const size_t row = brow * 128 + wr * 64 + m * 16 + l4 * 4 + j;
                const float val = acc[m][n][j] + bv;
                const size_t idx = trans ? (col * ldc + row) : (row * ldc + col);
                ((u16*)g.C[z])[idx] = f2bf(val);
            }
        }
}

// ---------------------------------------------------------------- GEMM C = A @ Bt^T (+bias), BK=64 (R4 structure)
template<int OUT_BF16, int HAS_BIAS>
__global__ __launch_bounds__(256, 2) void gemm64(G3 g, int K) {
    __shared__ __align__(16) u16 As[3][128 * 64];
    __shared__ __align__(16) u16 Bs[3][64 * 64];
    const int z = blockIdx.z;
    const u16* __restrict__ A = g.A[z];
    const u16* __restrict__ Bt = g.Bt[z];
    const int tid = threadIdx.x, lane = tid & 63, wid = tid >> 6;
    const int l15 = lane & 15, l4 = lane >> 4;
    const int wr = wid >> 1, wc = wid & 1;
    const size_t brow = blockIdx.x, bcol = blockIdx.y;
    const int trow = tid >> 3;
    const int cswz = ((tid & 7) ^ (trow & 7)) * 8;
    const int sa = l15 & 7;

    const u16* Ag = A + (brow * 128 + trow) * (size_t)K + cswz;
    const u16* Bg = Bt + (bcol * 64 + trow) * (size_t)K + cswz;

    f32x4 acc[4][2];
#pragma unroll
    for (int m = 0; m < 4; m++)
#pragma unroll
        for (int n = 0; n < 2; n++) acc[m][n] = fzero4();

#define STG64(bi, k0) do { \
        __builtin_amdgcn_global_load_lds((gv_t*)(Ag + (k0)), (lv_t*)(&As[bi][tid * 8]), 16, 0, 0); \
        __builtin_amdgcn_global_load_lds((gv_t*)(Ag + (size_t)32 * K + (k0)), (lv_t*)(&As[bi][tid * 8 + 2048]), 16, 0, 0); \
        __builtin_amdgcn_global_load_lds((gv_t*)(Ag + (size_t)64 * K + (k0)), (lv_t*)(&As[bi][tid * 8 + 4096]), 16, 0, 0); \
        __builtin_amdgcn_global_load_lds((gv_t*)(Ag + (size_t)96 * K + (k0)), (lv_t*)(&As[bi][tid * 8 + 6144]), 16, 0, 0); \
        __builtin_amdgcn_global_load_lds((gv_t*)(Bg + (k0)), (lv_t*)(&Bs[bi][tid * 8]), 16, 0, 0); \
        __builtin_amdgcn_global_load_lds((gv_t*)(Bg + (size_t)32 * K + (k0)), (lv_t*)(&Bs[bi][tid * 8 + 2048]), 16, 0, 0); \
    } while (0)

    const int NT = K / 64;
    STG64(0, 0);
    STG64(1, 64);
    int cur = 0, pf = 2;
    for (int t = 0; t < NT; ++t) {
        if (t + 1 < NT) waitv<6>(); else waitv<0>();
        BAR();
        bf16x8 a[4][2], b[2][2];
#pragma unroll
        for (int m = 0; m < 4; m++)
#pragma unroll
            for (int kk = 0; kk < 2; kk++)
                a[m][kk] = *(const bf16x8*)&As[cur][(wr * 64 + m * 16 + l15) * 64 + (((kk * 4 + l4) ^ sa) * 8)];
#pragma unroll
        for (int n = 0; n < 2; n++)
#pragma unroll
            for (int kk = 0; kk < 2; kk++)
                b[n][kk] = *(const bf16x8*)&Bs[cur][(wc * 32 + n * 16 + l15) * 64 + (((kk * 4 + l4) ^ sa) * 8)];
        if (t + 2 < NT) STG64(pf, (t + 2) * 64);
        __builtin_amdgcn_s_setprio(1);
#pragma unroll
        for (int m = 0; m < 4; m++)
#pragma unroll
            for (int n = 0; n < 2; n++) {
                acc[m][n] = __builtin_amdgcn_mfma_f32_16x16x32_bf16(a[m][0], b[n][0], acc[m][n], 0, 0, 0);
                acc[m][n] = __builtin_amdgcn_mfma_f32_16x16x32_bf16(a[m][1], b[n][1], acc[m][n], 0, 0, 0);
            }
        __builtin_amdgcn_s_setprio(0);
        cur = (cur == 2) ? 0 : cur + 1;
        pf = (pf == 2) ? 0 : pf + 1;
    }
#undef STG64

    const int trans = g.trans[z];
    const size_t ldc = g.ldc[z];
    const float* bias = g.bias[z];
#pragma unroll
    for (int m = 0; m < 4; m++)
#pragma unroll
        for (int n = 0; n < 2; n++) {
            const size_t col = bcol * 64 + wc * 32 + n * 16 + l15;
            const float bv = HAS_BIAS ? bias[col] : 0.f;
#pragma unroll
            for (int j = 0; j < 4; j++) {
                const size_t row = brow * 128 + wr * 64 + m * 16 + l4 * 4 + j;
                const float val = acc[m][n][j] + bv;
                if (OUT_BF16) {
                    const size_t idx = trans ? (col * ldc + row) : (row * ldc + col);
                    ((u16*)g.C[z])[idx] = f2bf(val);
                } else {
                    ((float*)g.C[z])[row * ldc + col] = val;
                }
            }
        }
}

// ---------------------------------------------------------------- rowsum: inv[h][i] = 1/(16 * sum_j exp(S_hij))
__global__ __launch_bounds__(256, 2) void rowsum_kernel(
    const u16* __restrict__ Q, const u16* __restrict__ Kb, float* __restrict__ inv)
{
    __shared__ __align__(16) u16 Qs[2][64 * 32];
    __shared__ __align__(16) u16 Ks[3][2][64 * 32];
    const int tid = threadIdx.x, lane = tid & 63, wid = tid >> 6;
    const int l15 = lane & 15, l4 = lane >> 4;
    const int h = blockIdx.y;
    const size_t r0 = (size_t)blockIdx.x * 64;
    const int srow = tid >> 2;
    const int scol = (tid & 3) * 8;

#define STGR(bi, it) do { \
        __builtin_amdgcn_global_load_lds( \
            (gv_t*)(Kb + ((size_t)(it) * 64 + srow) * D_MODEL + h * HEAD_DIM + scol), \
            (lv_t*)(Ks[bi][0] + tid * 8), 16, 0, 0); \
        __builtin_amdgcn_global_load_lds( \
            (gv_t*)(Kb + ((size_t)(it) * 64 + srow) * D_MODEL + h * HEAD_DIM + 32 + scol), \
            (lv_t*)(Ks[bi][1] + tid * 8), 16, 0, 0); \
    } while (0)

#pragma unroll
    for (int kk = 0; kk < 2; kk++)
        __builtin_amdgcn_global_load_lds(
            (gv_t*)(Q + (r0 + srow) * D_MODEL + h * HEAD_DIM + kk * 32 + scol),
            (lv_t*)(Qs[kk] + tid * 8), 16, 0, 0);
    STGR(0, 0);
    STGR(1, 1);
    waitv<4>();
    BAR();
    bf16x8 aq[2];
#pragma unroll
    for (int kk = 0; kk < 2; kk++)
        aq[kk] = *(const bf16x8*)&Qs[kk][(wid * 16 + l15) * 32 + l4 * 8];

    float psum[4] = {0.f, 0.f, 0.f, 0.f};
    const int NT = BATCH / 64;
    int cur = 0, pf = 2;
    for (int it = 0; it < NT; ++it) {
        if (it + 1 < NT) waitv<2>(); else waitv<0>();
        BAR();
        bf16x8 b0[4], b1[4];
#pragma unroll
        for (int n = 0; n < 4; n++) {
            b0[n] = *(const bf16x8*)&Ks[cur][0][(n * 16 + l15) * 32 + l4 * 8];
            b1[n] = *(const bf16x8*)&Ks[cur][1][(n * 16 + l15) * 32 + l4 * 8];
        }
        if (it + 2 < NT) STGR(pf, it + 2);
        __builtin_amdgcn_s_setprio(1);
        f32x4 s[4];
#pragma unroll
        for (int n = 0; n < 4; n++) {
            s[n] = fzero4();
            s[n] = __builtin_amdgcn_mfma_f32_16x16x32_bf16(aq[0], b0[n], s[n], 0, 0, 0);
            s[n] = __builtin_amdgcn_mfma_f32_16x16x32_bf16(aq[1], b1[n], s[n], 0, 0, 0);
        }
        __builtin_amdgcn_s_setprio(0);
#pragma unroll
        for (int n = 0; n < 4; n++)
#pragma unroll
            for (int j = 0; j < 4; j++) psum[j] += __expf(s[n][j] * 0.125f);
        cur = (cur == 2) ? 0 : cur + 1;
        pf = (pf == 2) ? 0 : pf + 1;
    }
#undef STGR
#pragma unroll
    for (int off = 8; off >= 1; off >>= 1)
#pragma unroll
        for (int j = 0; j < 4; j++) psum[j] += __shfl_xor(psum[j], off, 64);
    if (l15 == 0) {
#pragma unroll
        for (int j = 0; j < 4; j++)
            inv[(size_t)h * BATCH + r0 + wid * 16 + l4 * 4 + j] = 1.0f / (16.0f * psum[j]);
    }
}

// ---------------------------------------------------------------- A_mean: Am[i][j] = sum_h exp(S_hij) * inv[h][i]
__global__ __launch_bounds__(256, 2) void amean_kernel(
    const u16* __restrict__ Q, const u16* __restrict__ Kb,
    const float* __restrict__ inv, u16* __restrict__ Am)
{
    __shared__ __align__(16) u16 As[3][128 * 64];
    __shared__ __align__(16) u16 Bs[3][64 * 64];
    const int tid = threadIdx.x, lane = tid & 63, wid = tid >> 6;
    const int l15 = lane & 15, l4 = lane >> 4;
    const int wr = wid >> 1, wc = wid & 1;
    const size_t brow = blockIdx.x, bcol = blockIdx.y;
    const int trow = tid >> 3;
    const int cswz = ((tid & 7) ^ (trow & 7)) * 8;
    const int sa = l15 & 7;

    const u16* Ag = Q + (brow * 128 + trow) * (size_t)D_MODEL + cswz;
    const u16* Bg = Kb + (bcol * 64 + trow) * (size_t)D_MODEL + cswz;

#define STGM(bi, k0) do { \
        __builtin_amdgcn_global_load_lds((gv_t*)(Ag + (k0)), (lv_t*)(&As[bi][tid * 8]), 16, 0, 0); \
        __builtin_amdgcn_global_load_lds((gv_t*)(Ag + (size_t)32 * D_MODEL + (k0)), (lv_t*)(&As[bi][tid * 8 + 2048]), 16, 0, 0); \
        __builtin_amdgcn_global_load_lds((gv_t*)(Ag + (size_t)64 * D_MODEL + (k0)), (lv_t*)(&As[bi][tid * 8 + 4096]), 16, 0, 0); \
        __builtin_amdgcn_global_load_lds((gv_t*)(Ag + (size_t)96 * D_MODEL + (k0)), (lv_t*)(&As[bi][tid * 8 + 6144]), 16, 0, 0); \
        __builtin_amdgcn_global_load_lds((gv_t*)(Bg + (k0)), (lv_t*)(&Bs[bi][tid * 8]), 16, 0, 0); \
        __builtin_amdgcn_global_load_lds((gv_t*)(Bg + (size_t)32 * D_MODEL + (k0)), (lv_t*)(&Bs[bi][tid * 8 + 2048]), 16, 0, 0); \
    } while (0)

    float accA[4][2][4] = {};
    STGM(0, 0);
    STGM(1, 64);
    int cur = 0, pf = 2;
    const float SC = 0.125f * 1.44269504088896341f;

    for (int h = 0; h < NUM_HEADS; h++) {
        if (h + 1 < NUM_HEADS) waitv<6>(); else waitv<0>();
        BAR();
        bf16x8 a[4][2], b[2][2];
#pragma unroll
        for (int m = 0; m < 4; m++)
#pragma unroll
            for (int kk = 0; kk < 2; kk++)
                a[m][kk] = *(const bf16x8*)&As[cur][(wr * 64 + m * 16 + l15) * 64 + (((kk * 4 + l4) ^ sa) * 8)];
#pragma unroll
        for (int n = 0; n < 2; n++)
#pragma unroll
            for (int kk = 0; kk < 2; kk++)
                b[n][kk] = *(const bf16x8*)&Bs[cur][(wc * 32 + n * 16 + l15) * 64 + (((kk * 4 + l4) ^ sa) * 8)];
        if (h + 2 < NUM_HEADS) STGM(pf, (h + 2) * 64);
        __builtin_amdgcn_s_setprio(1);
        f32x4 acc[4][2];
#pragma unroll
        for (int m = 0; m < 4; m++)
#pragma unroll
            for (int n = 0; n < 2; n++) {
                acc[m][n] = fzero4();
                acc[m][n] = __builtin_amdgcn_mfma_f32_16x16x32_bf16(a[m][0], b[n][0], acc[m][n], 0, 0, 0);
                acc[m][n] = __builtin_amdgcn_mfma_f32_16x16x32_bf16(a[m][1], b[n][1], acc[m][n], 0, 0, 0);
            }
        __builtin_amdgcn_s_setprio(0);
#pragma unroll
        for (int m = 0; m < 4; m++) {
            const f32x4 iv = *(const f32x4*)&inv[(size_t)h * BATCH + brow * 128 + wr * 64 + m * 16 + l4 * 4];
#pragma unroll
            for (int n = 0; n < 2; n++)
#pragma unroll
                for (int j = 0; j < 4; j++)
                    accA[m][n][j] += exp2f(acc[m][n][j] * SC) * iv[j];
        }
        cur = (cur == 2) ? 0 : cur + 1;
        pf = (pf == 2) ? 0 : pf + 1;
    }
#undef STGM

#pragma unroll
    for (int m = 0; m < 4; m++)
#pragma unroll
        for (int n = 0; n < 2; n++)
#pragma unroll
            for (int j = 0; j < 4; j++) {
                const size_t row = brow * 128 + wr * 64 + m * 16 + l4 * 4 + j;
                const size_t col = bcol * 64 + wc * 32 + n * 16 + l15;
                Am[row * (size_t)BATCH + col] = f2bf(accA[m][n][j]);
            }
}

// ---------------------------------------------------------------- launch
extern "C" void kernel_launch(void* const* d_in, const int* in_sizes, int n_in,
                              void* d_out, int out_size, void* d_ws, size_t ws_size,
                              hipStream_t stream)
{
    const float* q  = (const float*)d_in[0];
    const float* k  = (const float*)d_in[1];
    const float* v  = (const float*)d_in[2];
    const float* Wq = (const float*)d_in[3];
    const float* bq = (const float*)d_in[4];
    const float* Wk = (const float*)d_in[5];
    const float* bk = (const float*)d_in[6];
    const float* Wv = (const float*)d_in[7];
    const float* bv = (const float*)d_in[8];
    const float* Wo = (const float*)d_in[9];
    const float* bo = (const float*)d_in[10];
    float* out = (float*)d_out;

    char* p = (char*)d_ws;
    u16* qb  = (u16*)p; p += (size_t)BATCH * D_MODEL * 2;
    u16* kb  = (u16*)p; p += (size_t)BATCH * D_MODEL * 2;
    u16* vb  = (u16*)p; p += (size_t)BATCH * D_MODEL * 2;
    u16* wqb = (u16*)p; p += (size_t)D_MODEL * D_MODEL * 2;
    u16* wkb = (u16*)p; p += (size_t)D_MODEL * D_MODEL * 2;
    u16* wvb = (u16*)p; p += (size_t)D_MODEL * D_MODEL * 2;
    u16* wob = (u16*)p; p += (size_t)D_MODEL * D_MODEL * 2;
    u16* Qb  = (u16*)p; p += (size_t)BATCH * D_MODEL * 2;
    u16* Kp  = (u16*)p; p += (size_t)BATCH * D_MODEL * 2;
    u16* VPt = (u16*)p; p += (size_t)D_MODEL * BATCH * 2;   // (1024, 2048)
    u16* Am  = (u16*)p; p += (size_t)BATCH * BATCH * 2;     // (2048, 2048) bf16
    u16* T   = (u16*)p; p += (size_t)BATCH * D_MODEL * 2;   // (2048, 1024) bf16
    float* inv = (float*)p;                                  // (16, 2048) fp32

    Conv7 ca;
    ca.src[0] = q;  ca.dst[0] = qb;  ca.n[0] = BATCH * D_MODEL;
    ca.src[1] = k;  ca.dst[1] = kb;  ca.n[1] = BATCH * D_MODEL;
    ca.src[2] = v;  ca.dst[2] = vb;  ca.n[2] = BATCH * D_MODEL;
    ca.src[3] = Wq; ca.dst[3] = wqb; ca.n[3] = D_MODEL * D_MODEL;
    ca.src[4] = Wk; ca.dst[4] = wkb; ca.n[4] = D_MODEL * D_MODEL;
    ca.src[5] = Wv; ca.dst[5] = wvb; ca.n[5] = D_MODEL * D_MODEL;
    ca.src[6] = Wo; ca.dst[6] = wob; ca.n[6] = D_MODEL * D_MODEL;
    convert_kernel<<<dim3(1024, 7), 256, 0, stream>>>(ca);

    // Q / K / VPt projections in one dispatch: 384 blocks of 128x128, 3 blocks/CU possible
    G3 pr;
    pr.A[0] = qb; pr.Bt[0] = wqb; pr.bias[0] = bq; pr.C[0] = Qb;  pr.trans[0] = 0; pr.ldc[0] = D_MODEL;
    pr.A[1] = kb; pr.Bt[1] = wkb; pr.bias[1] = bk; pr.C[1] = Kp;  pr.trans[1] = 0; pr.ldc[1] = D_MODEL;
    pr.A[2] = vb; pr.Bt[2] = wvb; pr.bias[2] = bv; pr.C[2] = VPt; pr.trans[2] = 1; pr.ldc[2] = BATCH;
    proj128_kernel<<<dim3(16, 8, 3), 256, 0, stream>>>(pr, D_MODEL);

    // inv[h][i] = 1 / (16 * l_hi)
    rowsum_kernel<<<dim3(BATCH / 64, NUM_HEADS), 256, 0, stream>>>(Qb, Kp, inv);
    // Am = mean_h softmax(S_h) — 512 blocks of 128x64
    amean_kernel<<<dim3(BATCH / 128, BATCH / 64), 256, 0, stream>>>(Qb, Kp, inv, Am);

    // T = Am @ VPt^T  (2048,1024) bf16 — 256 blocks, K=2048
    G3 gt;
    gt.A[0] = Am; gt.Bt[0] = VPt; gt.bias[0] = nullptr; gt.C[0] = T; gt.trans[0] = 0; gt.ldc[0] = D_MODEL;
    gt.A[1] = gt.A[0]; gt.Bt[1] = gt.Bt[0]; gt.bias[1] = nullptr; gt.C[1] = gt.C[0]; gt.trans[1] = 0; gt.ldc[1] = D_MODEL;
    gt.A[2] = gt.A[0]; gt.Bt[2] = gt.Bt[0]; gt.bias[2] = nullptr; gt.C[2] = gt.C[0]; gt.trans[2] = 0; gt.ldc[2] = D_MODEL;
    gemm64<1, 0><<<dim3(16, 16, 1), 256, 0, stream>>>(gt, BATCH);

    // out = T @ Wo^T + bo  (2048,1024) fp32 — 256 blocks, K=1024
    G3 go;
    go.A[0] = T; go.Bt[0] = wob; go.bias[0] = bo; go.C[0] = out; go.trans[0] = 0; go.ldc[0] = D_MODEL;
    go.A[1] = go.A[0]; go.Bt[1] = go.Bt[0]; go.bias[1] = go.bias[0]; go.C[1] = go.C[0]; go.trans[1] = 0; go.ldc[1] = D_MODEL;
    go.A[2] = go.A[0]; go.Bt[2] = go.Bt[0]; go.bias[2] = go.bias[0]; go.C[2] = go.C[0]; go.trans[2] = 0; go.ldc[2] = D_MODEL;
    gemm64<0, 1><<<dim3(16, 16, 1), 256, 0, stream>>>(go, D_MODEL);
}

// Round 10
// 106.351 us; speedup vs baseline: 1.1148x; 1.1148x over previous
//
#include <hip/hip_runtime.h>
#include <hip/hip_bf16.h>
#include <stdint.h>

#define D_MODEL 1024
#define NUM_HEADS 16
#define HEAD_DIM 64
#define BATCH 2048

typedef unsigned short u16;
typedef __bf16 bf16x8 __attribute__((ext_vector_type(8)));
typedef float f32x4 __attribute__((ext_vector_type(4)));
typedef u16 u16x8 __attribute__((ext_vector_type(8)));

typedef __attribute__((address_space(1))) void gv_t;
typedef __attribute__((address_space(3))) void lv_t;

__device__ __forceinline__ u16 f2bf(float f) {
    uint32_t u = __builtin_bit_cast(uint32_t, f);
    return (u16)((u + 0x7fffu + ((u >> 16) & 1u)) >> 16);
}
__device__ __forceinline__ f32x4 fzero4() { f32x4 v = {0.f, 0.f, 0.f, 0.f}; return v; }

template<int N> __device__ __forceinline__ void waitv() {
    if constexpr (N == 0) asm volatile("s_waitcnt vmcnt(0)" ::: "memory");
    else if constexpr (N == 2) asm volatile("s_waitcnt vmcnt(2)" ::: "memory");
    else if constexpr (N == 4) asm volatile("s_waitcnt vmcnt(4)" ::: "memory");
    else if constexpr (N == 6) asm volatile("s_waitcnt vmcnt(6)" ::: "memory");
}
#define BAR() do { __builtin_amdgcn_s_barrier(); __builtin_amdgcn_sched_barrier(0); } while (0)

// ---------------------------------------------------------------- convert fp32 -> bf16
struct Conv7 {
    const float* src[7];
    u16* dst[7];
    int n[7];
};

__global__ __launch_bounds__(256) void convert_kernel(Conv7 a) {
    const int y = blockIdx.y;
    const int n = a.n[y];
    const long base = (long)(blockIdx.x * 256 + threadIdx.x) * 8;
    if (base >= n) return;
    const float* s = a.src[y] + base;
    const float4 f0 = *(const float4*)s;
    const float4 f1 = *(const float4*)(s + 4);
    u16x8 o;
    o[0] = f2bf(f0.x); o[1] = f2bf(f0.y); o[2] = f2bf(f0.z); o[3] = f2bf(f0.w);
    o[4] = f2bf(f1.x); o[5] = f2bf(f1.y); o[6] = f2bf(f1.z); o[7] = f2bf(f1.w);
    *(u16x8*)(a.dst[y] + base) = o;
}

struct G3 {
    const u16* A[3];
    const u16* Bt[3];
    const float* bias[3];
    void* C[3];
    int trans[3];
    int ldc[3];
};

// ---------------------------------------------------------------- proj GEMM, 128x128 tile, BK=32 (R8 structure, proven)
__global__ __launch_bounds__(256, 3) void proj128_kernel(G3 g, int K) {
    __shared__ __align__(16) u16 As[3][128 * 32];
    __shared__ __align__(16) u16 Bs[3][128 * 32];
    const int z = blockIdx.z;
    const u16* __restrict__ A = g.A[z];
    const u16* __restrict__ Bt = g.Bt[z];
    const int tid = threadIdx.x, lane = tid & 63, wid = tid >> 6;
    const int l15 = lane & 15, l4 = lane >> 4;
    const int wr = wid >> 1, wc = wid & 1;
    const size_t brow = blockIdx.x, bcol = blockIdx.y;
    const int trow = tid >> 2;
    const int cswz = ((tid & 3) ^ (trow & 3)) * 8;
    const int sa = l15 & 3;

    const u16* Ag = A + (brow * 128 + trow) * (size_t)K + cswz;
    const u16* Bg = Bt + (bcol * 128 + trow) * (size_t)K + cswz;

    f32x4 acc[4][4];
#pragma unroll
    for (int m = 0; m < 4; m++)
#pragma unroll
        for (int n = 0; n < 4; n++) acc[m][n] = fzero4();

#define STGP(bi, k0) do { \
        __builtin_amdgcn_global_load_lds((gv_t*)(Ag + (k0)), (lv_t*)(&As[bi][tid * 8]), 16, 0, 0); \
        __builtin_amdgcn_global_load_lds((gv_t*)(Ag + (size_t)64 * K + (k0)), (lv_t*)(&As[bi][tid * 8 + 2048]), 16, 0, 0); \
        __builtin_amdgcn_global_load_lds((gv_t*)(Bg + (k0)), (lv_t*)(&Bs[bi][tid * 8]), 16, 0, 0); \
        __builtin_amdgcn_global_load_lds((gv_t*)(Bg + (size_t)64 * K + (k0)), (lv_t*)(&Bs[bi][tid * 8 + 2048]), 16, 0, 0); \
    } while (0)

    const int NT = K / 32;
    STGP(0, 0);
    STGP(1, 32);
    int cur = 0, pf = 2;
    for (int t = 0; t < NT; ++t) {
        if (t + 1 < NT) waitv<4>(); else waitv<0>();
        BAR();
        bf16x8 a[4], b[4];
#pragma unroll
        for (int m = 0; m < 4; m++) {
            const int row = wr * 64 + m * 16 + l15;
            a[m] = *(const bf16x8*)&As[cur][row * 32 + ((l4 ^ sa) * 8)];
        }
#pragma unroll
        for (int n = 0; n < 4; n++) {
            const int row = wc * 64 + n * 16 + l15;
            b[n] = *(const bf16x8*)&Bs[cur][row * 32 + ((l4 ^ sa) * 8)];
        }
        if (t + 2 < NT) STGP(pf, (t + 2) * 32);
        __builtin_amdgcn_s_setprio(1);
#pragma unroll
        for (int m = 0; m < 4; m++)
#pragma unroll
            for (int n = 0; n < 4; n++)
                acc[m][n] = __builtin_amdgcn_mfma_f32_16x16x32_bf16(a[m], b[n], acc[m][n], 0, 0, 0);
        __builtin_amdgcn_s_setprio(0);
        cur = (cur == 2) ? 0 : cur + 1;
        pf = (pf == 2) ? 0 : pf + 1;
    }
#undef STGP

    const int trans = g.trans[z];
    const size_t ldc = g.ldc[z];
    const float* bias = g.bias[z];
#pragma unroll
    for (int m = 0; m < 4; m++)
#pragma unroll
        for (int n = 0; n < 4; n++) {
            const size_t col = bcol * 128 + wc * 64 + n * 16 + l15;
            const float bv = bias[col];
#pragma unroll
            for (int j = 0; j < 4; j++) {
                const size_t row = brow * 128 + wr * 64 + m * 16 + l4 * 4 + j;
                const float val = acc[m][n][j] + bv;
                const size_t idx = trans ? (col * ldc + row) : (row * ldc + col);
                ((u16*)g.C[z])[idx] = f2bf(val);
            }
        }
}

// ---------------------------------------------------------------- GEMM C = A @ Bt^T (+bias), BK=64 (R4 structure, proven)
template<int OUT_BF16, int HAS_BIAS>
__global__ __launch_bounds__(256, 2) void gemm64(G3 g, int K) {
    __shared__ __align__(16) u16 As[3][128 * 64];
    __shared__ __align__(16) u16 Bs[3][64 * 64];
    const int z = blockIdx.z;
    const u16* __restrict__ A = g.A[z];
    const u16* __restrict__ Bt = g.Bt[z];
    const int tid = threadIdx.x, lane = tid & 63, wid = tid >> 6;
    const int l15 = lane & 15, l4 = lane >> 4;
    const int wr = wid >> 1, wc = wid & 1;
    const size_t brow = blockIdx.x, bcol = blockIdx.y;
    const int trow = tid >> 3;
    const int cswz = ((tid & 7) ^ (trow & 7)) * 8;
    const int sa = l15 & 7;

    const u16* Ag = A + (brow * 128 + trow) * (size_t)K + cswz;
    const u16* Bg = Bt + (bcol * 64 + trow) * (size_t)K + cswz;

    f32x4 acc[4][2];
#pragma unroll
    for (int m = 0; m < 4; m++)
#pragma unroll
        for (int n = 0; n < 2; n++) acc[m][n] = fzero4();

#define STG64(bi, k0) do { \
        __builtin_amdgcn_global_load_lds((gv_t*)(Ag + (k0)), (lv_t*)(&As[bi][tid * 8]), 16, 0, 0); \
        __builtin_amdgcn_global_load_lds((gv_t*)(Ag + (size_t)32 * K + (k0)), (lv_t*)(&As[bi][tid * 8 + 2048]), 16, 0, 0); \
        __builtin_amdgcn_global_load_lds((gv_t*)(Ag + (size_t)64 * K + (k0)), (lv_t*)(&As[bi][tid * 8 + 4096]), 16, 0, 0); \
        __builtin_amdgcn_global_load_lds((gv_t*)(Ag + (size_t)96 * K + (k0)), (lv_t*)(&As[bi][tid * 8 + 6144]), 16, 0, 0); \
        __builtin_amdgcn_global_load_lds((gv_t*)(Bg + (k0)), (lv_t*)(&Bs[bi][tid * 8]), 16, 0, 0); \
        __builtin_amdgcn_global_load_lds((gv_t*)(Bg + (size_t)32 * K + (k0)), (lv_t*)(&Bs[bi][tid * 8 + 2048]), 16, 0, 0); \
    } while (0)

    const int NT = K / 64;
    STG64(0, 0);
    STG64(1, 64);
    int cur = 0, pf = 2;
    for (int t = 0; t < NT; ++t) {
        if (t + 1 < NT) waitv<6>(); else waitv<0>();
        BAR();
        bf16x8 a[4][2], b[2][2];
#pragma unroll
        for (int m = 0; m < 4; m++)
#pragma unroll
            for (int kk = 0; kk < 2; kk++)
                a[m][kk] = *(const bf16x8*)&As[cur][(wr * 64 + m * 16 + l15) * 64 + (((kk * 4 + l4) ^ sa) * 8)];
#pragma unroll
        for (int n = 0; n < 2; n++)
#pragma unroll
            for (int kk = 0; kk < 2; kk++)
                b[n][kk] = *(const bf16x8*)&Bs[cur][(wc * 32 + n * 16 + l15) * 64 + (((kk * 4 + l4) ^ sa) * 8)];
        if (t + 2 < NT) STG64(pf, (t + 2) * 64);
        __builtin_amdgcn_s_setprio(1);
#pragma unroll
        for (int m = 0; m < 4; m++)
#pragma unroll
            for (int n = 0; n < 2; n++) {
                acc[m][n] = __builtin_amdgcn_mfma_f32_16x16x32_bf16(a[m][0], b[n][0], acc[m][n], 0, 0, 0);
                acc[m][n] = __builtin_amdgcn_mfma_f32_16x16x32_bf16(a[m][1], b[n][1], acc[m][n], 0, 0, 0);
            }
        __builtin_amdgcn_s_setprio(0);
        cur = (cur == 2) ? 0 : cur + 1;
        pf = (pf == 2) ? 0 : pf + 1;
    }
#undef STG64

    const int trans = g.trans[z];
    const size_t ldc = g.ldc[z];
    const float* bias = g.bias[z];
#pragma unroll
    for (int m = 0; m < 4; m++)
#pragma unroll
        for (int n = 0; n < 2; n++) {
            const size_t col = bcol * 64 + wc * 32 + n * 16 + l15;
            const float bv = HAS_BIAS ? bias[col] : 0.f;
#pragma unroll
            for (int j = 0; j < 4; j++) {
                const size_t row = brow * 128 + wr * 64 + m * 16 + l4 * 4 + j;
                const float val = acc[m][n][j] + bv;
                if (OUT_BF16) {
                    const size_t idx = trans ? (col * ldc + row) : (row * ldc + col);
                    ((u16*)g.C[z])[idx] = f2bf(val);
                } else {
                    ((float*)g.C[z])[row * ldc + col] = val;
                }
            }
        }
}

// ---------------------------------------------------------------- rowsum: inv[h][i] = 1/(16 * sum_j exp(S_hij))
__global__ __launch_bounds__(256, 2) void rowsum_kernel(
    const u16* __restrict__ Q, const u16* __restrict__ Kb, float* __restrict__ inv)
{
    __shared__ __align__(16) u16 Qs[2][64 * 32];
    __shared__ __align__(16) u16 Ks[3][2][64 * 32];
    const int tid = threadIdx.x, lane = tid & 63, wid = tid >> 6;
    const int l15 = lane & 15, l4 = lane >> 4;
    const int h = blockIdx.y;
    const size_t r0 = (size_t)blockIdx.x * 64;
    const int srow = tid >> 2;
    const int scol = (tid & 3) * 8;

#define STGR(bi, it) do { \
        __builtin_amdgcn_global_load_lds( \
            (gv_t*)(Kb + ((size_t)(it) * 64 + srow) * D_MODEL + h * HEAD_DIM + scol), \
            (lv_t*)(Ks[bi][0] + tid * 8), 16, 0, 0); \
        __builtin_amdgcn_global_load_lds( \
            (gv_t*)(Kb + ((size_t)(it) * 64 + srow) * D_MODEL + h * HEAD_DIM + 32 + scol), \
            (lv_t*)(Ks[bi][1] + tid * 8), 16, 0, 0); \
    } while (0)

#pragma unroll
    for (int kk = 0; kk < 2; kk++)
        __builtin_amdgcn_global_load_lds(
            (gv_t*)(Q + (r0 + srow) * D_MODEL + h * HEAD_DIM + kk * 32 + scol),
            (lv_t*)(Qs[kk] + tid * 8), 16, 0, 0);
    STGR(0, 0);
    STGR(1, 1);
    waitv<4>();
    BAR();
    bf16x8 aq[2];
#pragma unroll
    for (int kk = 0; kk < 2; kk++)
        aq[kk] = *(const bf16x8*)&Qs[kk][(wid * 16 + l15) * 32 + l4 * 8];

    float psum[4] = {0.f, 0.f, 0.f, 0.f};
    const int NT = BATCH / 64;
    int cur = 0, pf = 2;
    for (int it = 0; it < NT; ++it) {
        if (it + 1 < NT) waitv<2>(); else waitv<0>();
        BAR();
        bf16x8 b0[4], b1[4];
#pragma unroll
        for (int n = 0; n < 4; n++) {
            b0[n] = *(const bf16x8*)&Ks[cur][0][(n * 16 + l15) * 32 + l4 * 8];
            b1[n] = *(const bf16x8*)&Ks[cur][1][(n * 16 + l15) * 32 + l4 * 8];
        }
        if (it + 2 < NT) STGR(pf, it + 2);
        __builtin_amdgcn_s_setprio(1);
        f32x4 s[4];
#pragma unroll
        for (int n = 0; n < 4; n++) {
            s[n] = fzero4();
            s[n] = __builtin_amdgcn_mfma_f32_16x16x32_bf16(aq[0], b0[n], s[n], 0, 0, 0);
            s[n] = __builtin_amdgcn_mfma_f32_16x16x32_bf16(aq[1], b1[n], s[n], 0, 0, 0);
        }
        __builtin_amdgcn_s_setprio(0);
#pragma unroll
        for (int n = 0; n < 4; n++)
#pragma unroll
            for (int j = 0; j < 4; j++) psum[j] += __expf(s[n][j] * 0.125f);
        cur = (cur == 2) ? 0 : cur + 1;
        pf = (pf == 2) ? 0 : pf + 1;
    }
#undef STGR
#pragma unroll
    for (int off = 8; off >= 1; off >>= 1)
#pragma unroll
        for (int j = 0; j < 4; j++) psum[j] += __shfl_xor(psum[j], off, 64);
    if (l15 == 0) {
#pragma unroll
        for (int j = 0; j < 4; j++)
            inv[(size_t)h * BATCH + r0 + wid * 16 + l4 * 4 + j] = 1.0f / (16.0f * psum[j]);
    }
}

// ---------------------------------------------------------------- merged: amean (by<32) + U^T GEMM (by>=32)
// amean: Am[i][j] = sum_h exp(S_hij) * inv[h][i], 128x64 tiles (R8 body).
// U^T = Wo @ VP^T, (1024,2048) bf16 — independent of the softmax chain, fills spare CUs.
// U block map (FIX vs R9): brow = bx>>1 (0..7), bcol = (by-32)*2 + (bx&1) (0..31) -> all 256 blocks.
__global__ __launch_bounds__(256, 2) void ameanu_kernel(
    const u16* __restrict__ Q, const u16* __restrict__ Kb,
    const float* __restrict__ inv, u16* __restrict__ Am,
    const u16* __restrict__ wob, const u16* __restrict__ VP, u16* __restrict__ Ut)
{
    __shared__ __align__(16) u16 As[3][128 * 64];
    __shared__ __align__(16) u16 Bs[3][64 * 64];
    const int tid = threadIdx.x, lane = tid & 63, wid = tid >> 6;
    const int l15 = lane & 15, l4 = lane >> 4;
    const int wr = wid >> 1, wc = wid & 1;
    const int bx = blockIdx.x, by = blockIdx.y;
    const int trow = tid >> 3;
    const int cswz = ((tid & 7) ^ (trow & 7)) * 8;
    const int sa = l15 & 7;

    if (by >= 32) {
        // ---- U path: C = wob @ VP^T, tile 128x64, K=1024 (gemm64 body)
        const size_t brow = bx >> 1;                          // 0..7
        const size_t bcol = (size_t)(by - 32) * 2 + (bx & 1); // 0..31
        const int K = D_MODEL;
        const u16* Ag = wob + (brow * 128 + trow) * (size_t)K + cswz;
        const u16* Bg = VP + (bcol * 64 + trow) * (size_t)K + cswz;

        f32x4 acc[4][2];
#pragma unroll
        for (int m = 0; m < 4; m++)
#pragma unroll
            for (int n = 0; n < 2; n++) acc[m][n] = fzero4();

#define STGU(bi, k0) do { \
        __builtin_amdgcn_global_load_lds((gv_t*)(Ag + (k0)), (lv_t*)(&As[bi][tid * 8]), 16, 0, 0); \
        __builtin_amdgcn_global_load_lds((gv_t*)(Ag + (size_t)32 * K + (k0)), (lv_t*)(&As[bi][tid * 8 + 2048]), 16, 0, 0); \
        __builtin_amdgcn_global_load_lds((gv_t*)(Ag + (size_t)64 * K + (k0)), (lv_t*)(&As[bi][tid * 8 + 4096]), 16, 0, 0); \
        __builtin_amdgcn_global_load_lds((gv_t*)(Ag + (size_t)96 * K + (k0)), (lv_t*)(&As[bi][tid * 8 + 6144]), 16, 0, 0); \
        __builtin_amdgcn_global_load_lds((gv_t*)(Bg + (k0)), (lv_t*)(&Bs[bi][tid * 8]), 16, 0, 0); \
        __builtin_amdgcn_global_load_lds((gv_t*)(Bg + (size_t)32 * K + (k0)), (lv_t*)(&Bs[bi][tid * 8 + 2048]), 16, 0, 0); \
    } while (0)

        const int NT = K / 64;
        STGU(0, 0);
        STGU(1, 64);
        int cur = 0, pf = 2;
        for (int t = 0; t < NT; ++t) {
            if (t + 1 < NT) waitv<6>(); else waitv<0>();
            BAR();
            bf16x8 a[4][2], b[2][2];
#pragma unroll
            for (int m = 0; m < 4; m++)
#pragma unroll
                for (int kk = 0; kk < 2; kk++)
                    a[m][kk] = *(const bf16x8*)&As[cur][(wr * 64 + m * 16 + l15) * 64 + (((kk * 4 + l4) ^ sa) * 8)];
#pragma unroll
            for (int n = 0; n < 2; n++)
#pragma unroll
                for (int kk = 0; kk < 2; kk++)
                    b[n][kk] = *(const bf16x8*)&Bs[cur][(wc * 32 + n * 16 + l15) * 64 + (((kk * 4 + l4) ^ sa) * 8)];
            if (t + 2 < NT) STGU(pf, (t + 2) * 64);
            __builtin_amdgcn_s_setprio(1);
#pragma unroll
            for (int m = 0; m < 4; m++)
#pragma unroll
                for (int n = 0; n < 2; n++) {
                    acc[m][n] = __builtin_amdgcn_mfma_f32_16x16x32_bf16(a[m][0], b[n][0], acc[m][n], 0, 0, 0);
                    acc[m][n] = __builtin_amdgcn_mfma_f32_16x16x32_bf16(a[m][1], b[n][1], acc[m][n], 0, 0, 0);
                }
            __builtin_amdgcn_s_setprio(0);
            cur = (cur == 2) ? 0 : cur + 1;
            pf = (pf == 2) ? 0 : pf + 1;
        }
#undef STGU

#pragma unroll
        for (int m = 0; m < 4; m++)
#pragma unroll
            for (int n = 0; n < 2; n++) {
                const size_t col = bcol * 64 + wc * 32 + n * 16 + l15;
#pragma unroll
                for (int j = 0; j < 4; j++) {
                    const size_t row = brow * 128 + wr * 64 + m * 16 + l4 * 4 + j;
                    Ut[row * (size_t)BATCH + col] = f2bf(acc[m][n][j]);
                }
            }
        return;
    }

    // ---- amean path (R8 body, unchanged)
    const size_t brow = bx, bcol = by;
    const u16* Ag = Q + (brow * 128 + trow) * (size_t)D_MODEL + cswz;
    const u16* Bg = Kb + (bcol * 64 + trow) * (size_t)D_MODEL + cswz;

#define STGM(bi, k0) do { \
        __builtin_amdgcn_global_load_lds((gv_t*)(Ag + (k0)), (lv_t*)(&As[bi][tid * 8]), 16, 0, 0); \
        __builtin_amdgcn_global_load_lds((gv_t*)(Ag + (size_t)32 * D_MODEL + (k0)), (lv_t*)(&As[bi][tid * 8 + 2048]), 16, 0, 0); \
        __builtin_amdgcn_global_load_lds((gv_t*)(Ag + (size_t)64 * D_MODEL + (k0)), (lv_t*)(&As[bi][tid * 8 + 4096]), 16, 0, 0); \
        __builtin_amdgcn_global_load_lds((gv_t*)(Ag + (size_t)96 * D_MODEL + (k0)), (lv_t*)(&As[bi][tid * 8 + 6144]), 16, 0, 0); \
        __builtin_amdgcn_global_load_lds((gv_t*)(Bg + (k0)), (lv_t*)(&Bs[bi][tid * 8]), 16, 0, 0); \
        __builtin_amdgcn_global_load_lds((gv_t*)(Bg + (size_t)32 * D_MODEL + (k0)), (lv_t*)(&Bs[bi][tid * 8 + 2048]), 16, 0, 0); \
    } while (0)

    float accA[4][2][4] = {};
    STGM(0, 0);
    STGM(1, 64);
    int cur = 0, pf = 2;
    const float SC = 0.125f * 1.44269504088896341f;

    for (int h = 0; h < NUM_HEADS; h++) {
        if (h + 1 < NUM_HEADS) waitv<6>(); else waitv<0>();
        BAR();
        bf16x8 a[4][2], b[2][2];
#pragma unroll
        for (int m = 0; m < 4; m++)
#pragma unroll
            for (int kk = 0; kk < 2; kk++)
                a[m][kk] = *(const bf16x8*)&As[cur][(wr * 64 + m * 16 + l15) * 64 + (((kk * 4 + l4) ^ sa) * 8)];
#pragma unroll
        for (int n = 0; n < 2; n++)
#pragma unroll
            for (int kk = 0; kk < 2; kk++)
                b[n][kk] = *(const bf16x8*)&Bs[cur][(wc * 32 + n * 16 + l15) * 64 + (((kk * 4 + l4) ^ sa) * 8)];
        if (h + 2 < NUM_HEADS) STGM(pf, (h + 2) * 64);
        __builtin_amdgcn_s_setprio(1);
        f32x4 acc[4][2];
#pragma unroll
        for (int m = 0; m < 4; m++)
#pragma unroll
            for (int n = 0; n < 2; n++) {
                acc[m][n] = fzero4();
                acc[m][n] = __builtin_amdgcn_mfma_f32_16x16x32_bf16(a[m][0], b[n][0], acc[m][n], 0, 0, 0);
                acc[m][n] = __builtin_amdgcn_mfma_f32_16x16x32_bf16(a[m][1], b[n][1], acc[m][n], 0, 0, 0);
            }
        __builtin_amdgcn_s_setprio(0);
#pragma unroll
        for (int m = 0; m < 4; m++) {
            const f32x4 iv = *(const f32x4*)&inv[(size_t)h * BATCH + brow * 128 + wr * 64 + m * 16 + l4 * 4];
#pragma unroll
            for (int n = 0; n < 2; n++)
#pragma unroll
                for (int j = 0; j < 4; j++)
                    accA[m][n][j] += exp2f(acc[m][n][j] * SC) * iv[j];
        }
        cur = (cur == 2) ? 0 : cur + 1;
        pf = (pf == 2) ? 0 : pf + 1;
    }
#undef STGM

#pragma unroll
    for (int m = 0; m < 4; m++)
#pragma unroll
        for (int n = 0; n < 2; n++)
#pragma unroll
            for (int j = 0; j < 4; j++) {
                const size_t row = brow * 128 + wr * 64 + m * 16 + l4 * 4 + j;
                const size_t col = bcol * 64 + wc * 32 + n * 16 + l15;
                Am[row * (size_t)BATCH + col] = f2bf(accA[m][n][j]);
            }
}

// ---------------------------------------------------------------- launch
extern "C" void kernel_launch(void* const* d_in, const int* in_sizes, int n_in,
                              void* d_out, int out_size, void* d_ws, size_t ws_size,
                              hipStream_t stream)
{
    const float* q  = (const float*)d_in[0];
    const float* k  = (const float*)d_in[1];
    const float* v  = (const float*)d_in[2];
    const float* Wq = (const float*)d_in[3];
    const float* bq = (const float*)d_in[4];
    const float* Wk = (const float*)d_in[5];
    const float* bk = (const float*)d_in[6];
    const float* Wv = (const float*)d_in[7];
    const float* bv = (const float*)d_in[8];
    const float* Wo = (const float*)d_in[9];
    const float* bo = (const float*)d_in[10];
    float* out = (float*)d_out;

    char* p = (char*)d_ws;
    u16* qb  = (u16*)p; p += (size_t)BATCH * D_MODEL * 2;
    u16* kb  = (u16*)p; p += (size_t)BATCH * D_MODEL * 2;
    u16* vb  = (u16*)p; p += (size_t)BATCH * D_MODEL * 2;
    u16* wqb = (u16*)p; p += (size_t)D_MODEL * D_MODEL * 2;
    u16* wkb = (u16*)p; p += (size_t)D_MODEL * D_MODEL * 2;
    u16* wvb = (u16*)p; p += (size_t)D_MODEL * D_MODEL * 2;
    u16* wob = (u16*)p; p += (size_t)D_MODEL * D_MODEL * 2;
    u16* Qb  = (u16*)p; p += (size_t)BATCH * D_MODEL * 2;
    u16* Kp  = (u16*)p; p += (size_t)BATCH * D_MODEL * 2;
    u16* VP  = (u16*)p; p += (size_t)BATCH * D_MODEL * 2;   // (2048, 1024) row-major
    u16* Am  = (u16*)p; p += (size_t)BATCH * BATCH * 2;     // (2048, 2048) bf16
    u16* Ut  = (u16*)p; p += (size_t)D_MODEL * BATCH * 2;   // U^T (1024, 2048) bf16
    float* inv = (float*)p;                                  // (16, 2048) fp32

    Conv7 ca;
    ca.src[0] = q;  ca.dst[0] = qb;  ca.n[0] = BATCH * D_MODEL;
    ca.src[1] = k;  ca.dst[1] = kb;  ca.n[1] = BATCH * D_MODEL;
    ca.src[2] = v;  ca.dst[2] = vb;  ca.n[2] = BATCH * D_MODEL;
    ca.src[3] = Wq; ca.dst[3] = wqb; ca.n[3] = D_MODEL * D_MODEL;
    ca.src[4] = Wk; ca.dst[4] = wkb; ca.n[4] = D_MODEL * D_MODEL;
    ca.src[5] = Wv; ca.dst[5] = wvb; ca.n[5] = D_MODEL * D_MODEL;
    ca.src[6] = Wo; ca.dst[6] = wob; ca.n[6] = D_MODEL * D_MODEL;
    convert_kernel<<<dim3(1024, 7), 256, 0, stream>>>(ca);

    // Q / K / VP projections in one dispatch (VP non-transposed)
    G3 pr;
    pr.A[0] = qb; pr.Bt[0] = wqb; pr.bias[0] = bq; pr.C[0] = Qb; pr.trans[0] = 0; pr.ldc[0] = D_MODEL;
    pr.A[1] = kb; pr.Bt[1] = wkb; pr.bias[1] = bk; pr.C[1] = Kp; pr.trans[1] = 0; pr.ldc[1] = D_MODEL;
    pr.A[2] = vb; pr.Bt[2] = wvb; pr.bias[2] = bv; pr.C[2] = VP; pr.trans[2] = 0; pr.ldc[2] = D_MODEL;
    proj128_kernel<<<dim3(16, 8, 3), 256, 0, stream>>>(pr, D_MODEL);

    // inv[h][i] = 1 / (16 * l_hi)
    rowsum_kernel<<<dim3(BATCH / 64, NUM_HEADS), 256, 0, stream>>>(Qb, Kp, inv);

    // Am = mean_h softmax(S_h)  (by<32, 512 blocks)  +  U^T = Wo @ VP^T  (by>=32, 256 blocks)
    ameanu_kernel<<<dim3(16, 48), 256, 0, stream>>>(Qb, Kp, inv, Am, wob, VP, Ut);

    // out = Am @ U + bo   (A=Am, Bt=U^T, K=2048), fp32 out — replaces the old T+out pair
    G3 go;
    go.A[0] = Am; go.Bt[0] = Ut; go.bias[0] = bo; go.C[0] = out; go.trans[0] = 0; go.ldc[0] = D_MODEL;
    go.A[1] = go.A[0]; go.Bt[1] = go.Bt[0]; go.bias[1] = go.bias[0]; go.C[1] = go.C[0]; go.trans[1] = 0; go.ldc[1] = D_MODEL;
    go.A[2] = go.A[0]; go.Bt[2] = go.Bt[0]; go.bias[2] = go.bias[0]; go.C[2] = go.C[0]; go.trans[2] = 0; go.ldc[2] = D_MODEL;
    gemm64<0, 1><<<dim3(16, 16, 1), 256, 0, stream>>>(go, BATCH);
}